// Round 2
// 406.960 us; speedup vs baseline: 1.0009x; 1.0009x over previous
//
#include <hip/hip_runtime.h>
#include <hip/hip_bf16.h>

#define N_TOTAL   131072
#define D         512
#define D_ATT     256
#define N_HEAD    4
#define N_CLASSES 53
#define BAG       16
#define M_TILE    64
#define THREADS   256
#define N_BLOCKS  (N_TOTAL / M_TILE)   // 2048
#define BK        32
#define K_ITERS   (D / BK)             // 16

typedef __attribute__((ext_vector_type(8))) short bf16x8;
typedef __attribute__((ext_vector_type(4))) float f32x4;

__device__ __forceinline__ unsigned short f2bf(float f) {
    __hip_bfloat16 h = __float2bfloat16(f);
    return *reinterpret_cast<unsigned short*>(&h);
}
// round-half-up bf16 pair pack: dst lo16 = bf16(a), hi16 = bf16(b)
__device__ __forceinline__ unsigned int pack_bf(float a, float b) {
    unsigned int ua = __float_as_uint(a) + 0x8000u;
    unsigned int ub = __float_as_uint(b) + 0x8000u;
    return __builtin_amdgcn_perm(ub, ua, 0x07060302u);
}

typedef __attribute__((address_space(3))) unsigned char lds_u8;
typedef __attribute__((address_space(1))) const unsigned char g_u8;
#define GLD16(G, L) __builtin_amdgcn_global_load_lds((g_u8*)(G), (lds_u8*)(L), 16, 0, 0)

// Prep: W1 [512][256] f32 -> W1T bf16 [256][512]
//       Wc [512][53]  f32 -> WcTb bf16 [64][512], rows 53..63 zero
__global__ void prep_kernel(const float* __restrict__ W1, const float* __restrict__ Wc,
                            unsigned short* __restrict__ W1T, unsigned short* __restrict__ WcTb) {
    int tid = blockIdx.x * 256 + threadIdx.x;
    if (tid < D * D_ATT) {
        int k = tid >> 8;        // 0..511
        int n = tid & 255;       // 0..255
        W1T[n * D + k] = f2bf(W1[k * D_ATT + n]);
    } else {
        int t2 = tid - D * D_ATT;          // 0..32767
        int n = t2 >> 9;                   // 0..63
        int k = t2 & 511;
        WcTb[n * D + k] = (n < N_CLASSES) ? f2bf(Wc[k * N_CLASSES + n])
                                          : (unsigned short)0;
    }
}

// A-tile: bf16 [64 rows][32 cols], row stride 80 B (5x16B -> slot (5r+quad)%8,
// uniform over the wave => conflict-free ds_read_b128 AND ds_write_b128).
#define A_STRIDE 80
#define A_TILE_B (M_TILE * A_STRIDE)   // 5120 B
__device__ __forceinline__ bf16x8 read_a16(const unsigned char* base, int r, int quad) {
    return *reinterpret_cast<const bf16x8*>(base + (unsigned)(r * A_STRIDE + quad * 16));
}
// B/C-fragment: row n, k = quad*8..+7, bf16 LDS tile (swizzled by (n>>1)&3)
__device__ __forceinline__ bf16x8 read_b_frag(const unsigned char* base, int n, int quad) {
    const int pos = quad ^ ((n >> 1) & 3);
    return *reinterpret_cast<const bf16x8*>(base + (unsigned)(n * 4 + pos) * 16u);
}

// One K-step: 16 s-GEMM MFMAs (64 rows x this wave's 64-col slice)
// + 4 y-GEMM MFMAs (all 64 rows x this wave's 16-class slice; reuses afr)
__device__ __forceinline__ void compute_tile(
        const unsigned char* bA, const unsigned char* bB, const unsigned char* bC,
        int wave, int l16, int quad, f32x4 acc[4][4], f32x4* accY) {
    bf16x8 afr[4];
    #pragma unroll
    for (int mi = 0; mi < 4; ++mi)
        afr[mi] = read_a16(bA, mi * 16 + l16, quad);
    bf16x8 bfr[4];
    #pragma unroll
    for (int ni = 0; ni < 4; ++ni)
        bfr[ni] = read_b_frag(bB, wave * 64 + ni * 16 + l16, quad);
    #pragma unroll
    for (int mi = 0; mi < 4; ++mi)
        #pragma unroll
        for (int ni = 0; ni < 4; ++ni)
            acc[mi][ni] = __builtin_amdgcn_mfma_f32_16x16x32_bf16(
                afr[mi], bfr[ni], acc[mi][ni], 0, 0, 0);
    bf16x8 cf = read_b_frag(bC, wave * 16 + l16, quad);   // classes wave*16 + l16
    #pragma unroll
    for (int mi = 0; mi < 4; ++mi)
        accY[mi] = __builtin_amdgcn_mfma_f32_16x16x32_bf16(afr[mi], cf, accY[mi], 0, 0, 0);
}

__global__ void __launch_bounds__(THREADS, 3)
fused_kernel(const float* __restrict__ x,
             const unsigned short* __restrict__ W1T,    // bf16 [256][512]
             const unsigned short* __restrict__ WcTb,   // bf16 [64][512]
             const float* __restrict__ W2,              // f32 [256][4]
             const float* __restrict__ bc,              // f32 [53]
             float* __restrict__ out)                   // f32 [8192][53]
{
    // Double-buffered staging, 50 KB total -> 3 blocks/CU (150 KB <= 160 KB).
    // A: bf16 [64][32] pad80 = 5120 B; B: bf16 [256][32] = 16 KB; C: bf16 [64][32] = 4 KB.
    __shared__ __align__(16) unsigned char lds[51200];
    unsigned char* bA0 = lds;
    unsigned char* bA1 = lds + 5120;
    unsigned char* bB0 = lds + 10240;
    unsigned char* bB1 = lds + 26624;
    unsigned char* bC0 = lds + 43008;
    unsigned char* bC1 = lds + 47104;

    const int tid  = threadIdx.x;
    const int wave = tid >> 6;          // 0..3 = col-slice (s) / class-slice (y)
    const int lane = tid & 63;
    const int quad = lane >> 4;
    const int l16  = lane & 15;
    const int row_base = blockIdx.x * M_TILE;

    // ---- A staging (reg-staged, f32->bf16 packed once): thread owns 8 consecutive f32 ----
    const int r_st = tid >> 2;          // row 0..63
    const int j_st = tid & 3;           // 16B-chunk col
    const float* gA = x + (size_t)(row_base + r_st) * D + j_st * 8;
    const unsigned aWoff = (unsigned)(r_st * A_STRIDE + j_st * 16);

    // ---- B/C staging via global_load_lds (global side carries the swizzle) ----
    // chunk c = tid + 256*i: n = c>>2, p = c&3, j = p ^ ((n>>1)&3).
    // Invariant: c -> c+256 adds 64 to n, leaves p and j unchanged
    // ((n>>1) grows by 32 => &3 unchanged), so gB_{i} = gB0 + i*65536 bytes.
    const char* gB0; const char* gC0; unsigned lB0;
    {
        int n = tid >> 2, p = tid & 3, j = p ^ ((n >> 1) & 3);
        gB0 = (const char*)(W1T  + (size_t)n * D + j * 8);
        gC0 = (const char*)(WcTb + (size_t)n * D + j * 8);
        lB0 = (unsigned)tid * 16u;
    }

    f32x4 acc[4][4] = {};    // s-GEMM: 64 rows x 64 cols (col slice = wave*64)
    f32x4 accY[4]   = {};    // y-GEMM: accY[mi] = bag mi rows, classes wave*16..+15
    float4 aR0a, aR0b, aR1a, aR1b;   // A reg sets: set s holds tile kt with kt&1 == s

#define LOAD_A(RA, RB, KT) do { \
        (RA) = *reinterpret_cast<const float4*>(gA + (KT) * BK);     \
        (RB) = *reinterpret_cast<const float4*>(gA + (KT) * BK + 4); \
    } while (0)

#define PACK_A(DST, RA, RB) do { \
        uint4 _pw; \
        _pw.x = pack_bf((RA).x, (RA).y); \
        _pw.y = pack_bf((RA).z, (RA).w); \
        _pw.z = pack_bf((RB).x, (RB).y); \
        _pw.w = pack_bf((RB).z, (RB).w); \
        *reinterpret_cast<uint4*>((DST) + aWoff) = _pw; \
    } while (0)

#define STAGE_BC(DB, DC, KT) do { \
        GLD16(gB0 +          (KT) * 64, (DB) + lB0);          \
        GLD16(gB0 +  65536 + (KT) * 64, (DB) + lB0 +  4096);  \
        GLD16(gB0 + 131072 + (KT) * 64, (DB) + lB0 +  8192);  \
        GLD16(gB0 + 196608 + (KT) * 64, (DB) + lB0 + 12288);  \
        GLD16(gC0 +          (KT) * 64, (DC) + lC0);          \
    } while (0)
    const unsigned lC0 = lB0;

    // 2-phase double buffer, compiler-managed sync: every __syncthreads carries
    // the full vmcnt/lgkm drain, so correctness is independent of spills.
    // Staging for kt+1 is issued BEFORE compute(kt) -> one compute phase of overlap.
#define BODY(KT) do { \
        STAGE_BC(((KT) & 1) ? bB0 : bB1, ((KT) & 1) ? bC0 : bC1, (KT) + 1); \
        if (((KT) & 1) == 0) { \
            PACK_A(bA1, aR1a, aR1b); \
            if ((KT) + 2 <= 15) LOAD_A(aR0a, aR0b, (KT) + 2); \
        } else { \
            PACK_A(bA0, aR0a, aR0b); \
            if ((KT) + 2 <= 15) LOAD_A(aR1a, aR1b, (KT) + 2); \
        } \
        compute_tile(((KT) & 1) ? bA1 : bA0, ((KT) & 1) ? bB1 : bB0, \
                     ((KT) & 1) ? bC1 : bC0, wave, l16, quad, acc, accY); \
        __syncthreads(); \
    } while (0)

    // ---- prologue: regs A(0), stage BC(0), regs A(1), pack A(0) ----
    LOAD_A(aR0a, aR0b, 0);
    STAGE_BC(bB0, bC0, 0);
    LOAD_A(aR1a, aR1b, 1);
    PACK_A(bA0, aR0a, aR0b);     // compiler waits the exact vmcnt for aR0
    __syncthreads();             // full drain: tile 0 resident

    BODY(0);  BODY(1);  BODY(2);  BODY(3);
    BODY(4);  BODY(5);  BODY(6);  BODY(7);
    BODY(8);  BODY(9);  BODY(10); BODY(11);
    BODY(12); BODY(13); BODY(14);

    // kt = 15: staged by BODY(14), drained at its barrier
    compute_tile(bA1, bB1, bC1, wave, l16, quad, acc, accY);

    // ---- epilogue LDS aliased into staging space ----
    // Sp @[0,4096) sits in bA0 (dead: kt=15 compute touches only the *1 buffers).
    // S/M/Den/W live at 5120.. and are written only after the next __syncthreads.
    float (*ldsSp)[M_TILE][N_HEAD] = reinterpret_cast<float (*)[M_TILE][N_HEAD]>(lds);
    float (*ldsS)[N_HEAD]   = reinterpret_cast<float (*)[N_HEAD]>(lds + 5120);
    float (*ldsM)[N_HEAD]   = reinterpret_cast<float (*)[N_HEAD]>(lds + 6144);
    float (*ldsDen)[N_HEAD] = reinterpret_cast<float (*)[N_HEAD]>(lds + 6208);
    float* ldsW             = reinterpret_cast<float*>(lds + 6272);

    // ---- s partials: tanh + W2, butterfly over 16 col-lanes ----
    {
        float4 w2r[4];
        #pragma unroll
        for (int ni = 0; ni < 4; ++ni)
            w2r[ni] = *reinterpret_cast<const float4*>(&W2[(wave * 64 + ni * 16 + l16) * 4]);

        #pragma unroll
        for (int mi = 0; mi < 4; ++mi) {
            float sp[4][4] = {};   // [r][h]
            #pragma unroll
            for (int ni = 0; ni < 4; ++ni) {
                f32x4 v = acc[mi][ni];
                #pragma unroll
                for (int r = 0; r < 4; ++r) {
                    float e = __expf(2.f * v[r]);
                    float t = 1.f - 2.f / (e + 1.f);   // tanh
                    sp[r][0] += t * w2r[ni].x;
                    sp[r][1] += t * w2r[ni].y;
                    sp[r][2] += t * w2r[ni].z;
                    sp[r][3] += t * w2r[ni].w;
                }
            }
            #pragma unroll
            for (int msk = 1; msk < 16; msk <<= 1)
                #pragma unroll
                for (int r = 0; r < 4; ++r)
                    #pragma unroll
                    for (int h = 0; h < 4; ++h)
                        sp[r][h] += __shfl_xor(sp[r][h], msk, 64);
            if (l16 == 0) {
                #pragma unroll
                for (int r = 0; r < 4; ++r) {
                    int row = mi * 16 + quad * 4 + r;
                    float4 v4 = {sp[r][0], sp[r][1], sp[r][2], sp[r][3]};
                    *reinterpret_cast<float4*>(&ldsSp[wave][row][0]) = v4;
                }
            }
        }
    }
    __syncthreads();

    // ---- combine wave partials ----
    {
        int row = tid >> 2, h = tid & 3;   // 256 threads = 64 rows x 4 heads
        ldsS[row][h] = ldsSp[0][row][h] + ldsSp[1][row][h]
                     + ldsSp[2][row][h] + ldsSp[3][row][h];
    }
    __syncthreads();

    // ---- per-bag per-head softmax stats ----
    if (tid < 4 * N_HEAD) {                 // 16 threads
        int bag = tid >> 2, head = tid & 3;
        float m = -1e30f;
        for (int i = 0; i < BAG; ++i)
            m = fmaxf(m, ldsS[bag * BAG + i][head]);
        float den = 0.f;
        for (int i = 0; i < BAG; ++i)
            den += __expf(ldsS[bag * BAG + i][head] - m);
        ldsM[bag][head] = m;
        ldsDen[bag][head] = 1.f / den;
    }
    __syncthreads();
    if (tid < M_TILE) {                      // 64 threads: w[row]
        int row = tid, bag = row >> 4;
        float w = 0.f;
        #pragma unroll
        for (int h = 0; h < 4; ++h)
            w += __expf(ldsS[row][h] - ldsM[bag][h]) * ldsDen[bag][h];
        ldsW[row] = 0.25f * w;
    }
    __syncthreads();

    // ---- logits: accY[mi] = bag mi (rows mi*16..+15), classes wave*16 + l16 ----
    {
        float p[4];
        #pragma unroll
        for (int mi = 0; mi < 4; ++mi) {
            f32x4 v = accY[mi];
            float s = 0.f;
            #pragma unroll
            for (int r = 0; r < 4; ++r)
                s += ldsW[mi * 16 + quad * 4 + r] * v[r];
            s += __shfl_xor(s, 16, 64);
            s += __shfl_xor(s, 32, 64);
            p[mi] = s;
        }
        if (quad == 0) {
            int c = wave * 16 + l16;
            if (c < N_CLASSES) {
                float b = bc[c];
                #pragma unroll
                for (int mi = 0; mi < 4; ++mi) {
                    size_t bag = (size_t)blockIdx.x * 4 + mi;
                    out[bag * N_CLASSES + c] = p[mi] + b;
                }
            }
        }
    }
#undef BODY
#undef STAGE_BC
#undef PACK_A
#undef LOAD_A
}

extern "C" void kernel_launch(void* const* d_in, const int* in_sizes, int n_in,
                              void* d_out, int out_size, void* d_ws, size_t ws_size,
                              hipStream_t stream) {
    const float* x  = (const float*)d_in[0];
    const float* W1 = (const float*)d_in[1];
    const float* W2 = (const float*)d_in[2];
    const float* Wc = (const float*)d_in[3];
    const float* bc = (const float*)d_in[4];

    unsigned short* W1T  = (unsigned short*)d_ws;                          // 262144 B
    unsigned short* WcTb = (unsigned short*)((char*)d_ws + 262144);        // 65536 B

    prep_kernel<<<dim3(640), dim3(256), 0, stream>>>(W1, Wc, W1T, WcTb);

    fused_kernel<<<dim3(N_BLOCKS), dim3(THREADS), 0, stream>>>(
        x, W1T, WcTb, W2, bc, (float*)d_out);
}